// Round 24
// baseline (102.902 us; speedup 1.0000x reference)
//
#include <hip/hip_runtime.h>
#include <math.h>

#define NN 2048
#define PP 4096
#define DD 128
#define SS 150
#define THR 204
#define CAP 512
#define EXP2C 2.8853900817779268f   // 2/ln(2): exp(2x) = 2^(EXP2C*x)

typedef float f32x4 __attribute__((ext_vector_type(4)));
typedef short s16x8 __attribute__((ext_vector_type(8)));

// ws layout (float offsets) — bf16 arrays are 4096*128 u16 = 262144 floats each
#define OFF_POOLN 0          // 524288 f32
#define OFF_WTT   524288     // 16384 f32
#define OFF_PB    540672     // 262144 floats (bf16 projected pool)
#define OFF_REFL  806912     // 4096
#define OFF_POSD  811008     // 4096
#define OFF_POOLB 1650688    // 262144 floats (bf16 normalized pool)
#define OFF_SIMS  1912832    // 4096*4096 f32 = 64 MB
#define OFF_LOSS  18690048   // 4096 f32 per-row losses

__device__ __forceinline__ unsigned fkey(float v) {
    unsigned u = __float_as_uint(v);
    return u ^ (unsigned)(((int)u >> 31) | 0x80000000);
}
__device__ __forceinline__ float fkinv(unsigned k) {
    unsigned u = (k & 0x80000000u) ? (k ^ 0x80000000u) : ~k;
    return __uint_as_float(u);
}
__device__ __forceinline__ unsigned short f2bf(float f) {
    unsigned u = __float_as_uint(f);
    u = (u + 0x7FFFu + ((u >> 16) & 1u)) >> 16;
    return (unsigned short)u;
}
__device__ __forceinline__ float bf2f(unsigned short h) {
    return __uint_as_float((unsigned)h << 16);
}
// value-linear monotone bin over [-1,1]: identical expression everywhere
__device__ __forceinline__ int binOf(float v) {
    int b = (int)fmaf(v, 512.f, 512.f);
    return min(max(b, 0), 1023);
}
// bank-swizzled index for bin-keyed LDS arrays: lane-owned bins l*16+j -> addr (j<<6)|l
__device__ __forceinline__ int SIDX(int b) {
    return ((b & 15) << 6) | (b >> 4);
}

// ---------------- prep: normalize pool rows -> f32 + bf16 ----------------
__global__ void prep_norm(const float* __restrict__ z1, const float* __restrict__ z2,
                          float* __restrict__ pool_n, unsigned short* __restrict__ poolb) {
    int b = blockIdx.x;
    int l = threadIdx.x;
    const float* src = (b < NN) ? z1 + (size_t)b * DD : z2 + (size_t)(b - NN) * DD;
    float2 v = *(const float2*)(src + 2 * l);
    float ss = v.x * v.x + v.y * v.y;
    #pragma unroll
    for (int mask = 1; mask < 64; mask <<= 1) ss += __shfl_xor(ss, mask);
    float inv = 1.0f / fmaxf(sqrtf(ss), 1e-12f);
    float2 nv; nv.x = v.x * inv; nv.y = v.y * inv;
    *(float2*)(pool_n + (size_t)b * DD + 2 * l) = nv;
    ((unsigned*)poolb)[(size_t)b * 64 + l] =
        (unsigned)f2bf(nv.x) | ((unsigned)f2bf(nv.y) << 16);
}

// ---------------- prep: transpose proj_w (fp32), layout [k][d] ----------------
__global__ void prep_wt(const float* __restrict__ pw, float* __restrict__ wtT) {
    int e = blockIdx.x * 256 + threadIdx.x;
    int k = e >> 7, d = e & 127;
    wtT[e] = pw[d * DD + k];
}

// ---------------- prep: Pb = bf16(z_pool @ W^T) ----------------
__global__ __launch_bounds__(256, 4) void prep_proj(
    const float* __restrict__ z1, const float* __restrict__ z2,
    const float* __restrict__ wtT, unsigned short* __restrict__ Pb) {
    __shared__ float z_sh[8][DD];
    int tid = threadIdx.x;
    int r0 = blockIdx.x * 8;
    for (int e = tid; e < 8 * DD; e += 256) {
        int rr = r0 + (e >> 7);
        z_sh[e >> 7][e & 127] = (rr < NN) ? z1[(size_t)rr * DD + (e & 127)]
                                          : z2[(size_t)(rr - NN) * DD + (e & 127)];
    }
    __syncthreads();
    int d = tid & 127, h = tid >> 7;
    float a0 = 0.f, a1 = 0.f, a2 = 0.f, a3 = 0.f;
    for (int k = 0; k < DD; k++) {
        float wv = wtT[k * DD + d];
        a0 += z_sh[4 * h + 0][k] * wv;
        a1 += z_sh[4 * h + 1][k] * wv;
        a2 += z_sh[4 * h + 2][k] * wv;
        a3 += z_sh[4 * h + 3][k] * wv;
    }
    Pb[(size_t)(r0 + 4 * h + 0) * DD + d] = f2bf(a0);
    Pb[(size_t)(r0 + 4 * h + 1) * DD + d] = f2bf(a1);
    Pb[(size_t)(r0 + 4 * h + 2) * DD + d] = f2bf(a2);
    Pb[(size_t)(r0 + 4 * h + 3) * DD + d] = f2bf(a3);
}

// ---------------- MFMA gram -> f32 sims; refl/posd on diag blocks ----------------
#define LDA 136
__global__ __launch_bounds__(256) void gram_mfma(
    const unsigned short* __restrict__ poolb, float* __restrict__ sims,
    float* __restrict__ refl, float* __restrict__ posd) {
    __shared__ short tiles[2 * 128 * LDA];
    short* As = tiles;
    short* Bs = tiles + 128 * LDA;

    int tid = threadIdx.x;
    int bi = blockIdx.x >> 5, bj = blockIdx.x & 31;
    int r0 = bi * 128, c0 = bj * 128;

    const unsigned short* gA = poolb + (size_t)r0 * DD;
    const unsigned short* gB = poolb + (size_t)c0 * DD;
    #pragma unroll
    for (int it = 0; it < 8; it++) {
        int g = it * 256 + tid;
        int row = g >> 4, ch = (g & 15) * 8;
        *(s16x8*)&As[row * LDA + ch] = *(const s16x8*)(gA + row * DD + ch);
        *(s16x8*)&Bs[row * LDA + ch] = *(const s16x8*)(gB + row * DD + ch);
    }
    __syncthreads();

    int l = tid & 63, w = tid >> 6;
    int wr = (w >> 1) * 64, wc = (w & 1) * 64;
    int lr = l & 15, lk = (l >> 4) * 8;

    f32x4 zero = {0.f, 0.f, 0.f, 0.f};
    f32x4 acc[4][4];
    #pragma unroll
    for (int m = 0; m < 4; m++)
        #pragma unroll
        for (int n = 0; n < 4; n++) acc[m][n] = zero;

    #pragma unroll
    for (int kk = 0; kk < 4; kk++) {
        int ko = kk * 32 + lk;
        s16x8 av[4], bv[4];
        #pragma unroll
        for (int m = 0; m < 4; m++)
            av[m] = *(const s16x8*)&As[(wr + m * 16 + lr) * LDA + ko];
        #pragma unroll
        for (int n = 0; n < 4; n++)
            bv[n] = *(const s16x8*)&Bs[(wc + n * 16 + lr) * LDA + ko];
        #pragma unroll
        for (int m = 0; m < 4; m++)
            #pragma unroll
            for (int n = 0; n < 4; n++)
                acc[m][n] = __builtin_amdgcn_mfma_f32_16x16x32_bf16(av[m], bv[n], acc[m][n], 0, 0, 0);
    }

    int fq = (l >> 4) * 4, fr = l & 15;

    #pragma unroll
    for (int m = 0; m < 4; m++)
        #pragma unroll
        for (int n = 0; n < 4; n++) {
            int grow = r0 + wr + m * 16 + fq;
            int gcol = c0 + wc + n * 16 + fr;
            size_t base = (size_t)grow * PP + gcol;
            #pragma unroll
            for (int reg = 0; reg < 4; reg++)
                sims[base + (size_t)reg * PP] = acc[m][n][reg];
        }

    if (r0 == c0 || c0 == (r0 ^ NN)) {
        #pragma unroll
        for (int m = 0; m < 4; m++)
            #pragma unroll
            for (int n = 0; n < 4; n++) {
                int grow = r0 + wr + m * 16 + fq;
                int gcol = c0 + wc + n * 16 + fr;
                #pragma unroll
                for (int reg = 0; reg < 4; reg++) {
                    float v = acc[m][n][reg];
                    if (gcol == grow + reg) refl[gcol] = v;
                    if (gcol == ((grow + reg) ^ NN)) posd[grow + reg] = v;
                }
            }
    }
}

// ---------------- fused: 512-thr port of round-19 selectloss (same phase algorithms) ----------------
union SMem {
    struct {
        int hist[2][1024];                 // 8 KB (swizzled index)
        unsigned long long cand2[CAP];     // 4 KB
        int start[1024];                   // 4 KB (swizzled index)
        int bincnt[1024];                  // 4 KB (swizzled index)
    } sel;                                 // 20 KB
    struct { float pn2[SS * 17]; float pdt[SS * 17]; } mix;   // 20.4 KB
};

__global__ __launch_bounds__(512) void selectloss(
    const float* __restrict__ sims, const unsigned short* __restrict__ Pb,
    const float* __restrict__ pool_n, const float* __restrict__ proj_b,
    const float* __restrict__ refl, const float* __restrict__ posd,
    const int* __restrict__ idx1, const int* __restrict__ idx2,
    float* __restrict__ losses) {
    __shared__ SMem sm;
    __shared__ int topk_sh[THR];
    __shared__ int idx_sh[2 * SS];
    __shared__ float part[8];
    __shared__ float red2[8];
    __shared__ float rpscal[2];

    int tid = threadIdx.x, w = tid >> 6, l = tid & 63;
    int hs = tid >> 8;                      // 2 hist copies
    int r = blockIdx.x;
    int i = r & (NN - 1);
    const int* idxp = ((r >= NN) ? idx2 : idx1) + (size_t)i * (2 * SS);

    // early independent loads — full 300-entry coverage
    for (int e = tid; e < 2 * SS; e += 512) idx_sh[e] = idxp[e];
    if (tid == 0) { rpscal[0] = refl[r]; rpscal[1] = posd[r]; }
    int gid = tid >> 4, sub = tid & 15, d0 = sub * 8;   // 32 groups of 16
    float qv[8], bv[8];
    *(float4*)&qv[0] = *(const float4*)(pool_n + (size_t)r * DD + d0);
    *(float4*)&qv[4] = *(const float4*)(pool_n + (size_t)r * DD + d0 + 4);
    *(float4*)&bv[0] = *(const float4*)(proj_b + d0);
    *(float4*)&bv[4] = *(const float4*)(proj_b + d0 + 4);

    const float4* rp = (const float4*)(sims + (size_t)r * PP);
    float4 va[2];
    va[0] = rp[tid];
    va[1] = rp[tid + 512];

    // negsum: exp-sum of full row (8 values/thread)
    float es = 0.f;
    #pragma unroll
    for (int j = 0; j < 2; j++) {
        es += __builtin_exp2f(EXP2C * va[j].x) + __builtin_exp2f(EXP2C * va[j].y)
            + __builtin_exp2f(EXP2C * va[j].z) + __builtin_exp2f(EXP2C * va[j].w);
    }
    #pragma unroll
    for (int mask = 1; mask < 64; mask <<= 1) es += __shfl_xor(es, mask);
    if (l == 0) part[w] = es;

    #pragma unroll
    for (int q = 0; q < 4; q++) ((int*)sm.sel.hist)[tid + q * 512] = 0;
    __syncthreads();   // barrier 1: hist zero

    // hist pass on value-linear bins (swizzled slots)
    #pragma unroll
    for (int j = 0; j < 2; j++) {
        atomicAdd(&sm.sel.hist[hs][SIDX(binOf(va[j].x))], 1);
        atomicAdd(&sm.sel.hist[hs][SIDX(binOf(va[j].y))], 1);
        atomicAdd(&sm.sel.hist[hs][SIDX(binOf(va[j].z))], 1);
        atomicAdd(&sm.sel.hist[hs][SIDX(binOf(va[j].w))], 1);
    }
    // zero bincnt while hist atomics drain
    #pragma unroll
    for (int q = 0; q < 2; q++) sm.sel.bincnt[tid + q * 512] = 0;
    __syncthreads();   // barrier 2: hist complete

    // per-wave redundant scan -> bthr; wave 0 also writes start[] (suffix counts).
    int bthr;
    {
        int b16[16];
        int s = 0;
        #pragma unroll
        for (int j = 0; j < 16; j++) {
            int a = (j << 6) | l;
            b16[j] = sm.sel.hist[0][a] + sm.sel.hist[1][a];
            s += b16[j];
        }
        int suf = s;
        #pragma unroll
        for (int off = 1; off < 64; off <<= 1) {
            int x = __shfl_down(suf, off);
            if (l + off < 64) suf += x;
        }
        int cum = suf - s;                 // # values in bins owned by lanes > l
        int found = 1024;
        int above = cum;                   // running suffix for start[]
        #pragma unroll
        for (int j = 15; j >= 0; j--) {
            if (w == 0) sm.sel.start[(j << 6) | l] = above;   // start[SIDX(l*16+j)]
            if (above < THR && THR <= above + b16[j]) found = l * 16 + j;
            above += b16[j];
        }
        #pragma unroll
        for (int off = 1; off < 64; off <<= 1)
            found = min(found, __shfl_xor(found, off));
        bthr = found;
    }
    __syncthreads();   // barrier 3: start[] + bincnt ready

    // collect candidates directly into bin-partitioned slots
    #pragma unroll
    for (int j = 0; j < 2; j++) {
        int col0 = (tid + j * 512) * 4;
        #pragma unroll
        for (int c = 0; c < 4; c++) {
            float v = (c == 0) ? va[j].x : (c == 1) ? va[j].y : (c == 2) ? va[j].z : va[j].w;
            int b = binOf(v);
            if (b >= bthr) {
                int bs = SIDX(b);
                int p = atomicAdd(&sm.sel.bincnt[bs], 1);
                int slot = sm.sel.start[bs] + p;
                if (slot < CAP)
                    sm.sel.cand2[slot] = ((unsigned long long)fkey(v) << 32)
                                       | (unsigned)(~(unsigned)(col0 + c));
            }
        }
    }
    __syncthreads();   // barrier 4: cand2 bin-partitioned

    // within-bin rank only (counting sort): 1 slot per thread (512 >= CAP)
    int C = min(sm.sel.start[SIDX(bthr)] + sm.sel.bincnt[SIDX(bthr)], CAP);
    if (tid < C) {
        unsigned long long me = sm.sel.cand2[tid];
        float v = fkinv((unsigned)(me >> 32));
        int bs = SIDX(binOf(v));
        int base = sm.sel.start[bs];
        int cnt = sm.sel.bincnt[bs];
        int pos = base;
        int end = min(base + cnt, CAP);
        for (int c = base; c < end; c++)
            pos += (sm.sel.cand2[c] > me) ? 1 : 0;
        if (pos < THR) topk_sh[pos] = (int)(~(unsigned)me);
    }
    __syncthreads();   // barrier 5: topk done; sel arrays dead -> mix may reuse

    // ---- mix + project(bf16 linear) + normalize + dot; LDS partials; 32 groups ----
    {
        s16x8 xr[5], yr[5];
        #pragma unroll
        for (int k = 0; k < 5; k++) {
            int t = gid + 32 * k;
            int tc = (t < SS) ? t : (SS - 1);
            xr[k] = *(const s16x8*)(Pb + (size_t)topk_sh[idx_sh[tc]] * DD + d0);
            yr[k] = *(const s16x8*)(Pb + (size_t)topk_sh[idx_sh[tc + SS]] * DD + d0);
        }
        #pragma unroll
        for (int k = 0; k < 5; k++) {
            int t = gid + 32 * k;
            float n2 = 0.f, dt = 0.f;
            #pragma unroll
            for (int kk = 0; kk < 8; kk++) {
                float h = fmaf(0.2f, bf2f((unsigned short)xr[k][kk]),
                          fmaf(0.8f, bf2f((unsigned short)yr[k][kk]), bv[kk]));
                n2 = fmaf(h, h, n2);
                dt = fmaf(h, qv[kk], dt);
            }
            if (t < SS) {
                sm.mix.pn2[t * 17 + sub] = n2;
                sm.mix.pdt[t * 17 + sub] = dt;
            }
        }
    }
    __syncthreads();   // barrier 6

    float wsum = 0.f;
    if (tid < SS) {
        float n2 = 0.f, dt = 0.f;
        #pragma unroll
        for (int k = 0; k < 16; k++) {
            n2 += sm.mix.pn2[tid * 17 + k];
            dt += sm.mix.pdt[tid * 17 + k];
        }
        wsum = __builtin_exp2f(EXP2C * dt * rsqrtf(fmaxf(n2, 1e-24f)));
    }
    #pragma unroll
    for (int mask = 1; mask < 64; mask <<= 1) wsum += __shfl_xor(wsum, mask);
    if (l == 0) red2[w] = wsum;
    __syncthreads();
    if (tid == 0) {
        float negm = red2[0] + red2[1] + red2[2] + red2[3]
                   + red2[4] + red2[5] + red2[6] + red2[7];
        float negsum = part[0] + part[1] + part[2] + part[3]
                     + part[4] + part[5] + part[6] + part[7];
        float den = negsum + negm - rpscal[0];
        losses[r] = logf(den) - 2.0f * rpscal[1];
    }
}

// ---------------- final: sum 4096 losses -> out ----------------
__global__ __launch_bounds__(1024) void reduce_loss(
    const float* __restrict__ losses, float* __restrict__ out) {
    __shared__ float ws[16];
    int tid = threadIdx.x, w = tid >> 6, l = tid & 63;
    float s = losses[tid] + losses[tid + 1024] + losses[tid + 2048] + losses[tid + 3072];
    #pragma unroll
    for (int mask = 1; mask < 64; mask <<= 1) s += __shfl_xor(s, mask);
    if (l == 0) ws[w] = s;
    __syncthreads();
    if (tid == 0) {
        float tot = 0.f;
        #pragma unroll
        for (int q = 0; q < 16; q++) tot += ws[q];
        out[0] = tot * (1.0f / 4096.0f);
    }
}

extern "C" void kernel_launch(void* const* d_in, const int* in_sizes, int n_in,
                              void* d_out, int out_size, void* d_ws, size_t ws_size,
                              hipStream_t stream) {
    const float* z1  = (const float*)d_in[0];
    const float* z2  = (const float*)d_in[1];
    const float* pw  = (const float*)d_in[2];
    const float* pb  = (const float*)d_in[3];
    const int* idx1  = (const int*)d_in[4];
    const int* idx2  = (const int*)d_in[5];
    float* out = (float*)d_out;

    float* wsf = (float*)d_ws;
    float* pool_n  = wsf + OFF_POOLN;
    float* wtT     = wsf + OFF_WTT;
    unsigned short* Pb = (unsigned short*)(wsf + OFF_PB);
    float* rfl     = wsf + OFF_REFL;
    float* psd     = wsf + OFF_POSD;
    unsigned short* poolb = (unsigned short*)(wsf + OFF_POOLB);
    float* sims    = wsf + OFF_SIMS;
    float* losses  = wsf + OFF_LOSS;

    prep_norm<<<PP, 64, 0, stream>>>(z1, z2, pool_n, poolb);
    prep_wt<<<64, 256, 0, stream>>>(pw, wtT);
    prep_proj<<<PP / 8, 256, 0, stream>>>(z1, z2, wtT, Pb);
    gram_mfma<<<1024, 256, 0, stream>>>(poolb, sims, rfl, psd);
    selectloss<<<PP, 512, 0, stream>>>(sims, Pb, pool_n, pb, rfl, psd,
                                       idx1, idx2, losses);
    reduce_loss<<<1, 1024, 0, stream>>>(losses, out);
}

// Round 25
// 84.077 us; speedup vs baseline: 1.2239x; 1.2239x over previous
//
#include <hip/hip_runtime.h>
#include <math.h>

#define NN 2048
#define PP 4096
#define DD 128
#define SS 150
#define THR 204
#define CAP 512
#define EXP2C 2.8853900817779268f   // 2/ln(2): exp(2x) = 2^(EXP2C*x)

typedef float f32x4 __attribute__((ext_vector_type(4)));
typedef short s16x8 __attribute__((ext_vector_type(8)));

// ws layout (float offsets) — bf16 arrays are 4096*128 u16 = 262144 floats each
#define OFF_POOLN 0          // 524288 f32
#define OFF_WTT   524288     // 16384 f32
#define OFF_PB    540672     // 262144 floats (bf16 projected pool)
#define OFF_REFL  806912     // 4096
#define OFF_POSD  811008     // 4096
#define OFF_POOLB 1650688    // 262144 floats (bf16 normalized pool)
#define OFF_SIMS  1912832    // 4096*4096 f32 = 64 MB
#define OFF_LOSS  18690048   // 4096 f32 per-row losses

__device__ __forceinline__ unsigned fkey(float v) {
    unsigned u = __float_as_uint(v);
    return u ^ (unsigned)(((int)u >> 31) | 0x80000000);
}
__device__ __forceinline__ float fkinv(unsigned k) {
    unsigned u = (k & 0x80000000u) ? (k ^ 0x80000000u) : ~k;
    return __uint_as_float(u);
}
__device__ __forceinline__ unsigned short f2bf(float f) {
    unsigned u = __float_as_uint(f);
    u = (u + 0x7FFFu + ((u >> 16) & 1u)) >> 16;
    return (unsigned short)u;
}
__device__ __forceinline__ float bf2f(unsigned short h) {
    return __uint_as_float((unsigned)h << 16);
}
// value-linear monotone bin over [-1,1]: identical expression everywhere
__device__ __forceinline__ int binOf(float v) {
    int b = (int)fmaf(v, 512.f, 512.f);
    return min(max(b, 0), 1023);
}
// bank-swizzled index for bin-keyed LDS arrays: lane-owned bins l*16+j -> addr (j<<6)|l
__device__ __forceinline__ int SIDX(int b) {
    return ((b & 15) << 6) | (b >> 4);
}

// ---------------- prep: normalize pool rows -> f32 + bf16 ----------------
__global__ void prep_norm(const float* __restrict__ z1, const float* __restrict__ z2,
                          float* __restrict__ pool_n, unsigned short* __restrict__ poolb) {
    int b = blockIdx.x;
    int l = threadIdx.x;
    const float* src = (b < NN) ? z1 + (size_t)b * DD : z2 + (size_t)(b - NN) * DD;
    float2 v = *(const float2*)(src + 2 * l);
    float ss = v.x * v.x + v.y * v.y;
    #pragma unroll
    for (int mask = 1; mask < 64; mask <<= 1) ss += __shfl_xor(ss, mask);
    float inv = 1.0f / fmaxf(sqrtf(ss), 1e-12f);
    float2 nv; nv.x = v.x * inv; nv.y = v.y * inv;
    *(float2*)(pool_n + (size_t)b * DD + 2 * l) = nv;
    ((unsigned*)poolb)[(size_t)b * 64 + l] =
        (unsigned)f2bf(nv.x) | ((unsigned)f2bf(nv.y) << 16);
}

// ---------------- prep: transpose proj_w (fp32), layout [k][d] ----------------
__global__ void prep_wt(const float* __restrict__ pw, float* __restrict__ wtT) {
    int e = blockIdx.x * 256 + threadIdx.x;
    int k = e >> 7, d = e & 127;
    wtT[e] = pw[d * DD + k];
}

// ---------------- prep: Pb = bf16(z_pool @ W^T) ----------------
__global__ __launch_bounds__(256, 4) void prep_proj(
    const float* __restrict__ z1, const float* __restrict__ z2,
    const float* __restrict__ wtT, unsigned short* __restrict__ Pb) {
    __shared__ float z_sh[8][DD];
    int tid = threadIdx.x;
    int r0 = blockIdx.x * 8;
    for (int e = tid; e < 8 * DD; e += 256) {
        int rr = r0 + (e >> 7);
        z_sh[e >> 7][e & 127] = (rr < NN) ? z1[(size_t)rr * DD + (e & 127)]
                                          : z2[(size_t)(rr - NN) * DD + (e & 127)];
    }
    __syncthreads();
    int d = tid & 127, h = tid >> 7;
    float a0 = 0.f, a1 = 0.f, a2 = 0.f, a3 = 0.f;
    for (int k = 0; k < DD; k++) {
        float wv = wtT[k * DD + d];
        a0 += z_sh[4 * h + 0][k] * wv;
        a1 += z_sh[4 * h + 1][k] * wv;
        a2 += z_sh[4 * h + 2][k] * wv;
        a3 += z_sh[4 * h + 3][k] * wv;
    }
    Pb[(size_t)(r0 + 4 * h + 0) * DD + d] = f2bf(a0);
    Pb[(size_t)(r0 + 4 * h + 1) * DD + d] = f2bf(a1);
    Pb[(size_t)(r0 + 4 * h + 2) * DD + d] = f2bf(a2);
    Pb[(size_t)(r0 + 4 * h + 3) * DD + d] = f2bf(a3);
}

// ---------------- MFMA gram -> f32 sims; refl/posd on diag blocks ----------------
#define LDA 136
__global__ __launch_bounds__(256) void gram_mfma(
    const unsigned short* __restrict__ poolb, float* __restrict__ sims,
    float* __restrict__ refl, float* __restrict__ posd) {
    __shared__ short tiles[2 * 128 * LDA];
    short* As = tiles;
    short* Bs = tiles + 128 * LDA;

    int tid = threadIdx.x;
    int bi = blockIdx.x >> 5, bj = blockIdx.x & 31;
    int r0 = bi * 128, c0 = bj * 128;

    const unsigned short* gA = poolb + (size_t)r0 * DD;
    const unsigned short* gB = poolb + (size_t)c0 * DD;
    #pragma unroll
    for (int it = 0; it < 8; it++) {
        int g = it * 256 + tid;
        int row = g >> 4, ch = (g & 15) * 8;
        *(s16x8*)&As[row * LDA + ch] = *(const s16x8*)(gA + row * DD + ch);
        *(s16x8*)&Bs[row * LDA + ch] = *(const s16x8*)(gB + row * DD + ch);
    }
    __syncthreads();

    int l = tid & 63, w = tid >> 6;
    int wr = (w >> 1) * 64, wc = (w & 1) * 64;
    int lr = l & 15, lk = (l >> 4) * 8;

    f32x4 zero = {0.f, 0.f, 0.f, 0.f};
    f32x4 acc[4][4];
    #pragma unroll
    for (int m = 0; m < 4; m++)
        #pragma unroll
        for (int n = 0; n < 4; n++) acc[m][n] = zero;

    #pragma unroll
    for (int kk = 0; kk < 4; kk++) {
        int ko = kk * 32 + lk;
        s16x8 av[4], bv[4];
        #pragma unroll
        for (int m = 0; m < 4; m++)
            av[m] = *(const s16x8*)&As[(wr + m * 16 + lr) * LDA + ko];
        #pragma unroll
        for (int n = 0; n < 4; n++)
            bv[n] = *(const s16x8*)&Bs[(wc + n * 16 + lr) * LDA + ko];
        #pragma unroll
        for (int m = 0; m < 4; m++)
            #pragma unroll
            for (int n = 0; n < 4; n++)
                acc[m][n] = __builtin_amdgcn_mfma_f32_16x16x32_bf16(av[m], bv[n], acc[m][n], 0, 0, 0);
    }

    int fq = (l >> 4) * 4, fr = l & 15;

    #pragma unroll
    for (int m = 0; m < 4; m++)
        #pragma unroll
        for (int n = 0; n < 4; n++) {
            int grow = r0 + wr + m * 16 + fq;
            int gcol = c0 + wc + n * 16 + fr;
            size_t base = (size_t)grow * PP + gcol;
            #pragma unroll
            for (int reg = 0; reg < 4; reg++)
                sims[base + (size_t)reg * PP] = acc[m][n][reg];
        }

    if (r0 == c0 || c0 == (r0 ^ NN)) {
        #pragma unroll
        for (int m = 0; m < 4; m++)
            #pragma unroll
            for (int n = 0; n < 4; n++) {
                int grow = r0 + wr + m * 16 + fq;
                int gcol = c0 + wc + n * 16 + fr;
                #pragma unroll
                for (int reg = 0; reg < 4; reg++) {
                    float v = acc[m][n][reg];
                    if (gcol == grow + reg) refl[gcol] = v;
                    if (gcol == ((grow + reg) ^ NN)) posd[grow + reg] = v;
                }
            }
    }
}

// ---------------- fused: top-204 (counting-sort rank, swizzled bins) + negsum + mix/dot/loss ----------------
union SMem {
    struct {
        int hist[2][1024];                 // 8 KB (swizzled index)
        unsigned long long cand2[CAP];     // 4 KB
        int start[1024];                   // 4 KB (swizzled index)
        int bincnt[1024];                  // 4 KB (swizzled index)
    } sel;                                 // 20 KB
    struct { float pn2[SS * 17]; float pdt[SS * 17]; } mix;   // 20.4 KB
};

__global__ __launch_bounds__(256) void selectloss(
    const float* __restrict__ sims, const unsigned short* __restrict__ Pb,
    const float* __restrict__ pool_n, const float* __restrict__ proj_b,
    const float* __restrict__ refl, const float* __restrict__ posd,
    const int* __restrict__ idx1, const int* __restrict__ idx2,
    float* __restrict__ losses) {
    __shared__ SMem sm;
    __shared__ int topk_sh[THR];
    __shared__ int idx_sh[2 * SS];
    __shared__ float part[4];
    __shared__ float red2[4];
    __shared__ float rpscal[2];

    int tid = threadIdx.x, w = tid >> 6, l = tid & 63;
    int hs = tid >> 7;
    int r = blockIdx.x;
    int i = r & (NN - 1);
    const int* idxp = ((r >= NN) ? idx2 : idx1) + (size_t)i * (2 * SS);

    // early independent loads — full 300-entry coverage
    for (int e = tid; e < 2 * SS; e += 256) idx_sh[e] = idxp[e];
    if (tid == 0) { rpscal[0] = refl[r]; rpscal[1] = posd[r]; }
    int gid = tid >> 4, sub = tid & 15, d0 = sub * 8;
    float qv[8], bv[8];
    *(float4*)&qv[0] = *(const float4*)(pool_n + (size_t)r * DD + d0);
    *(float4*)&qv[4] = *(const float4*)(pool_n + (size_t)r * DD + d0 + 4);
    *(float4*)&bv[0] = *(const float4*)(proj_b + d0);
    *(float4*)&bv[4] = *(const float4*)(proj_b + d0 + 4);

    const float4* rp = (const float4*)(sims + (size_t)r * PP);
    float4 va[4];
    #pragma unroll
    for (int j = 0; j < 4; j++) va[j] = rp[tid + j * 256];

    // negsum: exp-sum of full row
    float es = 0.f;
    #pragma unroll
    for (int j = 0; j < 4; j++) {
        es += __builtin_exp2f(EXP2C * va[j].x) + __builtin_exp2f(EXP2C * va[j].y)
            + __builtin_exp2f(EXP2C * va[j].z) + __builtin_exp2f(EXP2C * va[j].w);
    }
    #pragma unroll
    for (int mask = 1; mask < 64; mask <<= 1) es += __shfl_xor(es, mask);
    if (l == 0) part[w] = es;

    #pragma unroll
    for (int q = 0; q < 4; q++) sm.sel.hist[0][tid + q * 256] = 0;
    #pragma unroll
    for (int q = 0; q < 4; q++) sm.sel.hist[1][tid + q * 256] = 0;
    __syncthreads();   // barrier 1: hist zero

    // hist pass on value-linear bins (swizzled slots)
    #pragma unroll
    for (int j = 0; j < 4; j++) {
        atomicAdd(&sm.sel.hist[hs][SIDX(binOf(va[j].x))], 1);
        atomicAdd(&sm.sel.hist[hs][SIDX(binOf(va[j].y))], 1);
        atomicAdd(&sm.sel.hist[hs][SIDX(binOf(va[j].z))], 1);
        atomicAdd(&sm.sel.hist[hs][SIDX(binOf(va[j].w))], 1);
    }
    // zero bincnt while hist atomics drain
    #pragma unroll
    for (int q = 0; q < 4; q++) sm.sel.bincnt[tid + q * 256] = 0;
    __syncthreads();   // barrier 2: hist complete

    // per-wave scan -> bthr; wave 0 also writes start[] (suffix counts).
    // lane l owns bins [l*16, l*16+16); swizzled addr (j<<6)|l -> 2-way bank alias only
    int bthr;
    {
        int b16[16];
        int s = 0;
        #pragma unroll
        for (int j = 0; j < 16; j++) {
            int a = (j << 6) | l;
            b16[j] = sm.sel.hist[0][a] + sm.sel.hist[1][a];
            s += b16[j];
        }
        int suf = s;
        #pragma unroll
        for (int off = 1; off < 64; off <<= 1) {
            int x = __shfl_down(suf, off);
            if (l + off < 64) suf += x;
        }
        int cum = suf - s;                 // # values in bins owned by lanes > l
        int found = 1024;
        int above = cum;                   // running suffix for start[]
        #pragma unroll
        for (int j = 15; j >= 0; j--) {
            if (w == 0) sm.sel.start[(j << 6) | l] = above;   // start[SIDX(l*16+j)]
            if (above < THR && THR <= above + b16[j]) found = l * 16 + j;
            above += b16[j];
        }
        #pragma unroll
        for (int off = 1; off < 64; off <<= 1)
            found = min(found, __shfl_xor(found, off));
        bthr = found;
    }
    __syncthreads();   // barrier 3: start[] + bincnt ready

    // collect candidates directly into bin-partitioned slots
    #pragma unroll
    for (int j = 0; j < 4; j++) {
        int col0 = (tid + j * 256) * 4;
        #pragma unroll
        for (int c = 0; c < 4; c++) {
            float v = (c == 0) ? va[j].x : (c == 1) ? va[j].y : (c == 2) ? va[j].z : va[j].w;
            int b = binOf(v);
            if (b >= bthr) {
                int bs = SIDX(b);
                int p = atomicAdd(&sm.sel.bincnt[bs], 1);
                int slot = sm.sel.start[bs] + p;
                if (slot < CAP)
                    sm.sel.cand2[slot] = ((unsigned long long)fkey(v) << 32)
                                       | (unsigned)(~(unsigned)(col0 + c));
            }
        }
    }
    __syncthreads();   // barrier 4: cand2 bin-partitioned

    // within-bin rank only (counting sort): pos = start[b] + #same-bin beats
    int C = min(sm.sel.start[SIDX(bthr)] + sm.sel.bincnt[SIDX(bthr)], CAP);
    #pragma unroll
    for (int o = 0; o < 2; o++) {
        int s = tid + o * 256;
        if (s < C) {
            unsigned long long me = sm.sel.cand2[s];
            float v = fkinv((unsigned)(me >> 32));
            int bs = SIDX(binOf(v));
            int base = sm.sel.start[bs];
            int cnt = sm.sel.bincnt[bs];
            int pos = base;
            int end = min(base + cnt, CAP);
            for (int c = base; c < end; c++)
                pos += (sm.sel.cand2[c] > me) ? 1 : 0;
            if (pos < THR) topk_sh[pos] = (int)(~(unsigned)me);
        }
    }
    __syncthreads();   // barrier 5: topk done; sel arrays dead -> mix may reuse

    // ---- mix + project(bf16 linear) + normalize + dot; LDS partials ----
    #pragma unroll
    for (int half = 0; half < 2; half++) {
        s16x8 xr[5], yr[5];
        #pragma unroll
        for (int k = 0; k < 5; k++) {
            int t = gid + 16 * (half * 5 + k);
            int tc = (t < SS) ? t : (SS - 1);
            xr[k] = *(const s16x8*)(Pb + (size_t)topk_sh[idx_sh[tc]] * DD + d0);
            yr[k] = *(const s16x8*)(Pb + (size_t)topk_sh[idx_sh[tc + SS]] * DD + d0);
        }
        #pragma unroll
        for (int k = 0; k < 5; k++) {
            int t = gid + 16 * (half * 5 + k);
            float n2 = 0.f, dt = 0.f;
            #pragma unroll
            for (int kk = 0; kk < 8; kk++) {
                float h = fmaf(0.2f, bf2f((unsigned short)xr[k][kk]),
                          fmaf(0.8f, bf2f((unsigned short)yr[k][kk]), bv[kk]));
                n2 = fmaf(h, h, n2);
                dt = fmaf(h, qv[kk], dt);
            }
            if (t < SS) {
                sm.mix.pn2[t * 17 + sub] = n2;
                sm.mix.pdt[t * 17 + sub] = dt;
            }
        }
    }
    __syncthreads();   // barrier 6

    float wsum = 0.f;
    if (tid < SS) {
        float n2 = 0.f, dt = 0.f;
        #pragma unroll
        for (int k = 0; k < 16; k++) {
            n2 += sm.mix.pn2[tid * 17 + k];
            dt += sm.mix.pdt[tid * 17 + k];
        }
        wsum = __builtin_exp2f(EXP2C * dt * rsqrtf(fmaxf(n2, 1e-24f)));
    }
    #pragma unroll
    for (int mask = 1; mask < 64; mask <<= 1) wsum += __shfl_xor(wsum, mask);
    if (l == 0) red2[w] = wsum;
    __syncthreads();
    if (tid == 0) {
        float negm = red2[0] + red2[1] + red2[2] + red2[3];
        float negsum = part[0] + part[1] + part[2] + part[3];
        float den = negsum + negm - rpscal[0];
        losses[r] = logf(den) - 2.0f * rpscal[1];
    }
}

// ---------------- final: sum 4096 losses -> out ----------------
__global__ __launch_bounds__(1024) void reduce_loss(
    const float* __restrict__ losses, float* __restrict__ out) {
    __shared__ float ws[16];
    int tid = threadIdx.x, w = tid >> 6, l = tid & 63;
    float s = losses[tid] + losses[tid + 1024] + losses[tid + 2048] + losses[tid + 3072];
    #pragma unroll
    for (int mask = 1; mask < 64; mask <<= 1) s += __shfl_xor(s, mask);
    if (l == 0) ws[w] = s;
    __syncthreads();
    if (tid == 0) {
        float tot = 0.f;
        #pragma unroll
        for (int q = 0; q < 16; q++) tot += ws[q];
        out[0] = tot * (1.0f / 4096.0f);
    }
}

extern "C" void kernel_launch(void* const* d_in, const int* in_sizes, int n_in,
                              void* d_out, int out_size, void* d_ws, size_t ws_size,
                              hipStream_t stream) {
    const float* z1  = (const float*)d_in[0];
    const float* z2  = (const float*)d_in[1];
    const float* pw  = (const float*)d_in[2];
    const float* pb  = (const float*)d_in[3];
    const int* idx1  = (const int*)d_in[4];
    const int* idx2  = (const int*)d_in[5];
    float* out = (float*)d_out;

    float* wsf = (float*)d_ws;
    float* pool_n  = wsf + OFF_POOLN;
    float* wtT     = wsf + OFF_WTT;
    unsigned short* Pb = (unsigned short*)(wsf + OFF_PB);
    float* rfl     = wsf + OFF_REFL;
    float* psd     = wsf + OFF_POSD;
    unsigned short* poolb = (unsigned short*)(wsf + OFF_POOLB);
    float* sims    = wsf + OFF_SIMS;
    float* losses  = wsf + OFF_LOSS;

    prep_norm<<<PP, 64, 0, stream>>>(z1, z2, pool_n, poolb);
    prep_wt<<<64, 256, 0, stream>>>(pw, wtT);
    prep_proj<<<PP / 8, 256, 0, stream>>>(z1, z2, wtT, Pb);
    gram_mfma<<<1024, 256, 0, stream>>>(poolb, sims, rfl, psd);
    selectloss<<<PP, 256, 0, stream>>>(sims, Pb, pool_n, pb, rfl, psd,
                                       idx1, idx2, losses);
    reduce_loss<<<1, 1024, 0, stream>>>(losses, out);
}